// Round 3
// baseline (488.588 us; speedup 1.0000x reference)
//
#include <hip/hip_runtime.h>
#include <math.h>

// Phase quantizer, v2 (STEPS=2), f32 in/out.
// R4 == R3 with compile fix: __builtin_nontemporal_* requires a clang native
//     vector type, not HIP's float4 class -> use ext_vector_type(4) f32x4 at
//     the nontemporal access sites.
// R3: (a) last-block-done pattern: K1/K2's final block reduces the 4096
//         partials in-kernel (48 KB read ONCE, overlapped with drain) ->
//         removes both 1-block reduce dispatches. Counters zeroed by one
//         8-byte hipMemsetAsync. 5 dispatches -> 4 (memset + 3 kernels).
//     (b) K3 uses non-temporal loads/stores: output (256 MB, never re-read)
//         no longer evicts the input residue in L3, so K3's re-read hits
//         Infinity Cache more often.
//     Per-element numerics identical to R1.

#define NM_PI     3.14159265358979323846f
#define NM_PI2_4  2.46740110027233965468f   // (pi/2)^2
#define NM_PISQ   9.86960440108935861883f   // pi^2

#define NBLK 4096
#define TPB  256

typedef float f32x4 __attribute__((ext_vector_type(4)));

// atan(r) for r in [0,1], A&S 4.4.49, |err| <= 1e-5 rad.
__device__ __forceinline__ float atan_poly(float r) {
  float r2 = r * r;
  float q = 0.0208351f;
  q = fmaf(q, r2, -0.0851330f);
  q = fmaf(q, r2, 0.1801410f);
  q = fmaf(q, r2, -0.3302995f);
  q = fmaf(q, r2, 0.9998660f);
  return r * q;
}

// Soft assignment directions (softmax over 4 phase centers), branchless.
// k_t = pi/tau, c1 = exp(-(pi/2)^2/tau), c2 = exp(-pi^2/tau).
__device__ __forceinline__ void soft_dirs(float x, float y, float k_t,
                                          float c1, float c2,
                                          float& dre, float& dim) {
  float ax = fabsf(x), ay = fabsf(y);
  float hi = fmaxf(ax, ay), lo = fminf(ax, ay);
  float r = lo * __builtin_amdgcn_rcpf(fmaxf(hi, 1e-30f));
  float u = atan_poly(r);                    // angle from dominant axis
  float P = __expf(k_t * u);
  float Pi = __builtin_amdgcn_rcpf(P);
  float wo = c2 * P * P;                     // opposite axis
  float wp = c1 * P;                         // near perpendicular (minor sign)
  float wq = c1 * Pi;                        // far perpendicular
  float inv_sum = __builtin_amdgcn_rcpf(1.0f + wo + wp + wq);
  float dmaj = (1.0f - wo) * inv_sum;
  float dmin = (wp - wq) * inv_sum;
  bool xdom = (ax >= ay);
  float sx = copysignf(1.0f, x), sy = copysignf(1.0f, y);
  dre = sx * (xdom ? dmaj : dmin);
  dim = sy * (xdom ? dmin : dmaj);
}

__device__ __forceinline__ float finalize_s(float sum, unsigned cnt) {
  float c = (float)(cnt > 0u ? cnt : 1u);
  float s = sum * __builtin_amdgcn_rcpf(c);
  s = (cnt > 0u) ? s : 0.0f;
  return fmaxf(s, 1e-6f);
}

// In-block all-reduce (TPB=256 -> 4 waves); result valid in ALL threads.
// Trailing __syncthreads makes back-to-back calls safe (LDS reuse).
__device__ __forceinline__ void block_allreduce3(float& sre, float& sim,
                                                 unsigned& cnt) {
  #pragma unroll
  for (int o = 32; o > 0; o >>= 1) {
    sre += __shfl_down(sre, o);
    sim += __shfl_down(sim, o);
    cnt += __shfl_down(cnt, o);
  }
  __shared__ float rf0[4];
  __shared__ float rf1[4];
  __shared__ unsigned ru[4];
  int wave = threadIdx.x >> 6;
  int lane = threadIdx.x & 63;
  if (lane == 0) { rf0[wave] = sre; rf1[wave] = sim; ru[wave] = cnt; }
  __syncthreads();
  sre = rf0[0] + rf0[1] + rf0[2] + rf0[3];
  sim = rf1[0] + rf1[1] + rf1[2] + rf1[3];
  cnt = ru[0] + ru[1] + ru[2] + ru[3];
  __syncthreads();
}

// Publish this block's partial; the LAST block to finish reduces all NBLK
// partials (once!) and writes the finalized scales. Release/acquire via
// __threadfence around the device-scope atomicAdd (standard last-block-done).
__device__ __forceinline__ void publish_and_maybe_finalize(
    float sre, float sim, unsigned cnt,
    float* __restrict__ psre, float* __restrict__ psim,
    unsigned* __restrict__ pcnt,
    unsigned* __restrict__ counter, unsigned nm,
    float* __restrict__ finals) {
  __shared__ unsigned last;
  if (threadIdx.x == 0) {
    psre[blockIdx.x] = sre;
    psim[blockIdx.x] = sim;
    pcnt[blockIdx.x] = cnt;
    __threadfence();                       // release partials device-wide
    last = (atomicAdd(counter, 1u) == (unsigned)(NBLK - 1)) ? 1u : 0u;
  }
  __syncthreads();
  if (last) {
    __threadfence();                       // acquire all partials
    float a = 0.f, b = 0.f;
    unsigned c = 0u;
    for (int i = threadIdx.x; i < NBLK; i += TPB) {   // 16 iters
      a += psre[i];
      b += psim[i];
      c += pcnt[i];
    }
    block_allreduce3(a, b, c);
    if (threadIdx.x == 0) {
      finals[0] = finalize_s(a, c);
      finals[1] = finalize_s(b, nm - c);
    }
  }
}

// K1: step-1 scale partials. mask_real == (|y| <= |x|); no transcendentals.
__global__ __launch_bounds__(TPB) void pq_k1(const float4* __restrict__ wr,
                                             const float4* __restrict__ wi,
                                             int n4, float* __restrict__ psre,
                                             float* __restrict__ psim,
                                             unsigned* __restrict__ pcnt,
                                             unsigned* __restrict__ counter,
                                             unsigned nm,
                                             float* __restrict__ finals) {
  float sre = 0.f, sim = 0.f;
  unsigned cnt = 0u;
  int stride = gridDim.x * blockDim.x;
  for (int i = blockIdx.x * blockDim.x + threadIdx.x; i < n4; i += stride) {
    float4 r = wr[i], g = wi[i];
    float xs[4] = {r.x, r.y, r.z, r.w};
    float ys[4] = {g.x, g.y, g.z, g.w};
    #pragma unroll
    for (int k = 0; k < 4; ++k) {
      float ax = fabsf(xs[k]), ay = fabsf(ys[k]);
      bool is_re = (ay <= ax);
      sre += is_re ? ax : 0.f;
      sim += is_re ? 0.f : ay;
      cnt += is_re ? 1u : 0u;
    }
  }
  block_allreduce3(sre, sim, cnt);
  publish_and_maybe_finalize(sre, sim, cnt, psre, psim, pcnt, counter, nm,
                             finals);
}

// K2: recompute step 1 with finals1, accumulate step-2 scale partials.
__global__ __launch_bounds__(TPB) void pq_k2(const float4* __restrict__ wr,
                                             const float4* __restrict__ wi,
                                             int n4,
                                             const float* __restrict__ temp,
                                             const float* __restrict__ finals1,
                                             float* __restrict__ psre,
                                             float* __restrict__ psim,
                                             unsigned* __restrict__ pcnt,
                                             unsigned* __restrict__ counter,
                                             unsigned nm,
                                             float* __restrict__ finals2) {
  float s_re1 = finals1[0], s_im1 = finals1[1];
  float it = __builtin_amdgcn_rcpf(temp[0] + 1e-6f);
  float k_t = NM_PI * it;
  float c1 = __expf(-NM_PI2_4 * it);
  float c2 = __expf(-NM_PISQ * it);
  float sre = 0.f, sim = 0.f;
  unsigned cnt = 0u;
  int stride = gridDim.x * blockDim.x;
  for (int i = blockIdx.x * blockDim.x + threadIdx.x; i < n4; i += stride) {
    float4 r = wr[i], g = wi[i];
    float xs[4] = {r.x, r.y, r.z, r.w};
    float ys[4] = {g.x, g.y, g.z, g.w};
    #pragma unroll
    for (int k = 0; k < 4; ++k) {
      float x = xs[k], y = ys[k];
      float dre, dim;
      soft_dirs(x, y, k_t, c1, c2, dre, dim);
      float er = x - dre * s_re1;
      float ei = y - dim * s_im1;
      float ax = fabsf(er), ay = fabsf(ei);
      bool is_re = (ay <= ax);
      sre += is_re ? ax : 0.f;
      sim += is_re ? 0.f : ay;
      cnt += is_re ? 1u : 0u;
    }
  }
  block_allreduce3(sre, sim, cnt);
  publish_and_maybe_finalize(sre, sim, cnt, psre, psim, pcnt, counter, nm,
                             finals2);
}

// K3: recompute steps 1+2, write qw_real / qw_imag. Non-temporal loads
// (last consumer of input) and stores (output never re-read; don't evict
// the input residue from L3). Uses native ext_vector f32x4 for the
// nontemporal builtins (HIP float4 is a class -> rejected by the builtin).
__global__ __launch_bounds__(TPB) void pq_k3(const float4* __restrict__ wr,
                                             const float4* __restrict__ wi,
                                             int n4,
                                             const float* __restrict__ temp,
                                             const float* __restrict__ finals1,
                                             const float* __restrict__ finals2,
                                             float4* __restrict__ out) {
  const f32x4* wr4 = reinterpret_cast<const f32x4*>(wr);
  const f32x4* wi4 = reinterpret_cast<const f32x4*>(wi);
  f32x4* out4 = reinterpret_cast<f32x4*>(out);
  float s_re1 = finals1[0], s_im1 = finals1[1];
  float s_re2 = finals2[0], s_im2 = finals2[1];
  float it = __builtin_amdgcn_rcpf(temp[0] + 1e-6f);
  float k_t = NM_PI * it;
  float c1 = __expf(-NM_PI2_4 * it);
  float c2 = __expf(-NM_PISQ * it);
  int stride = gridDim.x * blockDim.x;
  for (int i = blockIdx.x * blockDim.x + threadIdx.x; i < n4; i += stride) {
    f32x4 r = __builtin_nontemporal_load(&wr4[i]);
    f32x4 g = __builtin_nontemporal_load(&wi4[i]);
    float xs[4] = {r.x, r.y, r.z, r.w};
    float ys[4] = {g.x, g.y, g.z, g.w};
    float qr[4], qi[4];
    #pragma unroll
    for (int k = 0; k < 4; ++k) {
      float x = xs[k], y = ys[k];
      float d1re, d1im;
      soft_dirs(x, y, k_t, c1, c2, d1re, d1im);
      float q1r = d1re * s_re1;
      float q1i = d1im * s_im1;
      float er = x - q1r;
      float ei = y - q1i;
      float d2re, d2im;
      soft_dirs(er, ei, k_t, c1, c2, d2re, d2im);
      qr[k] = fmaf(d2re, s_re2, q1r);
      qi[k] = fmaf(d2im, s_im2, q1i);
    }
    f32x4 o0 = {qr[0], qr[1], qr[2], qr[3]};
    f32x4 o1 = {qi[0], qi[1], qi[2], qi[3]};
    __builtin_nontemporal_store(o0, &out4[i]);
    __builtin_nontemporal_store(o1, &out4[n4 + i]);
  }
}

extern "C" void kernel_launch(void* const* d_in, const int* in_sizes, int n_in,
                              void* d_out, int out_size, void* d_ws, size_t ws_size,
                              hipStream_t stream) {
  const float4* wr = (const float4*)d_in[0];
  const float4* wi = (const float4*)d_in[1];
  const float* temp = (const float*)d_in[2];
  int nm = in_sizes[0];
  int n4 = nm / 4;

  // ws layout (4B words):
  //   [0..1]  finals1 (s_re1, s_im1)
  //   [2..3]  finals2 (s_re2, s_im2)
  //   [6]     counter1   [7] counter2   (zeroed by memset below)
  //   [8        .. 8+NB)     p1_sre
  //   [8+NB     .. 8+2NB)    p1_sim
  //   [8+2NB    .. 8+3NB)    p1_cnt (uint)
  //   [8+3NB    .. 8+6NB)    pass-2 partials, same order
  float* w32 = (float*)d_ws;
  unsigned* u32 = (unsigned*)d_ws;
  float* finals1 = w32 + 0;
  float* finals2 = w32 + 2;
  unsigned* counter1 = u32 + 6;
  unsigned* counter2 = u32 + 7;
  float* p1_sre = w32 + 8;
  float* p1_sim = p1_sre + NBLK;
  unsigned* p1_cnt = u32 + 8 + 2 * NBLK;
  float* p2_sre = w32 + 8 + 3 * NBLK;
  float* p2_sim = p2_sre + NBLK;
  unsigned* p2_cnt = u32 + 8 + 5 * NBLK;

  // Zero both done-counters (8 bytes starting at word 6).
  (void)hipMemsetAsync((void*)counter1, 0, 2 * sizeof(unsigned), stream);

  dim3 block(TPB);
  dim3 grid(NBLK);
  pq_k1<<<grid, block, 0, stream>>>(wr, wi, n4, p1_sre, p1_sim, p1_cnt,
                                    counter1, (unsigned)nm, finals1);
  pq_k2<<<grid, block, 0, stream>>>(wr, wi, n4, temp, finals1,
                                    p2_sre, p2_sim, p2_cnt,
                                    counter2, (unsigned)nm, finals2);
  pq_k3<<<grid, block, 0, stream>>>(wr, wi, n4, temp, finals1, finals2,
                                    (float4*)d_out);
}

// Round 4
// 182.301 us; speedup vs baseline: 2.6801x; 2.6801x over previous
//
#include <hip/hip_runtime.h>
#include <math.h>

// Phase quantizer, v2 (STEPS=2), f32 in/out.
// R5: exact R1 structure (5 dispatches: K1, 1-block reduce, K2, 1-block
//     reduce, K3 — proven 215.8us). R4's last-block-done pattern REVERTED:
//     device-scope __threadfence + atomicAdd forces cross-XCD L2
//     writeback/invalidate on every block (8 non-coherent L2s) -> pq_k1 went
//     45us -> 287us. Kernel boundaries are the cheap global barrier here.
//     Single isolated change vs R1: K3 uses NON-TEMPORAL STORES only
//     (output never re-read; don't let 256MB of stores evict the input
//     residue from Infinity Cache — R4 showed ~50% of input stays L3-resident
//     across iterations). K3 loads stay normal (next iteration's K1 re-reads
//     the input).

#define NM_PI     3.14159265358979323846f
#define NM_PI2_4  2.46740110027233965468f   // (pi/2)^2
#define NM_PISQ   9.86960440108935861883f   // pi^2

#define NBLK 4096
#define TPB  256

typedef float f32x4 __attribute__((ext_vector_type(4)));

// atan(r) for r in [0,1], A&S 4.4.49, |err| <= 1e-5 rad.
__device__ __forceinline__ float atan_poly(float r) {
  float r2 = r * r;
  float q = 0.0208351f;
  q = fmaf(q, r2, -0.0851330f);
  q = fmaf(q, r2, 0.1801410f);
  q = fmaf(q, r2, -0.3302995f);
  q = fmaf(q, r2, 0.9998660f);
  return r * q;
}

// Soft assignment directions (softmax over 4 phase centers), branchless.
// k_t = pi/tau, c1 = exp(-(pi/2)^2/tau), c2 = exp(-pi^2/tau).
__device__ __forceinline__ void soft_dirs(float x, float y, float k_t,
                                          float c1, float c2,
                                          float& dre, float& dim) {
  float ax = fabsf(x), ay = fabsf(y);
  float hi = fmaxf(ax, ay), lo = fminf(ax, ay);
  float r = lo * __builtin_amdgcn_rcpf(fmaxf(hi, 1e-30f));
  float u = atan_poly(r);                    // angle from dominant axis
  float P = __expf(k_t * u);
  float Pi = __builtin_amdgcn_rcpf(P);
  float wo = c2 * P * P;                     // opposite axis
  float wp = c1 * P;                         // near perpendicular (minor sign)
  float wq = c1 * Pi;                        // far perpendicular
  float inv_sum = __builtin_amdgcn_rcpf(1.0f + wo + wp + wq);
  float dmaj = (1.0f - wo) * inv_sum;
  float dmin = (wp - wq) * inv_sum;
  bool xdom = (ax >= ay);
  float sx = copysignf(1.0f, x), sy = copysignf(1.0f, y);
  dre = sx * (xdom ? dmaj : dmin);
  dim = sy * (xdom ? dmin : dmaj);
}

__device__ __forceinline__ float finalize_s(float sum, unsigned cnt) {
  float c = (float)(cnt > 0u ? cnt : 1u);
  float s = sum * __builtin_amdgcn_rcpf(c);
  s = (cnt > 0u) ? s : 0.0f;
  return fmaxf(s, 1e-6f);
}

// In-block reduction (up to 16 waves). Result valid in thread 0.
__device__ __forceinline__ void block_reduce3(float& sre, float& sim,
                                              unsigned& cnt) {
  #pragma unroll
  for (int o = 32; o > 0; o >>= 1) {
    sre += __shfl_down(sre, o);
    sim += __shfl_down(sim, o);
    cnt += __shfl_down(cnt, o);
  }
  __shared__ float rf0[16];
  __shared__ float rf1[16];
  __shared__ unsigned ru[16];
  int wave = threadIdx.x >> 6;
  int lane = threadIdx.x & 63;
  int nw = blockDim.x >> 6;
  if (lane == 0) { rf0[wave] = sre; rf1[wave] = sim; ru[wave] = cnt; }
  __syncthreads();
  if (threadIdx.x == 0) {
    float a = rf0[0], b = rf1[0];
    unsigned c = ru[0];
    for (int w = 1; w < nw; ++w) { a += rf0[w]; b += rf1[w]; c += ru[w]; }
    sre = a; sim = b; cnt = c;
  }
}

// K1: step-1 scale partials. mask_real == (|y| <= |x|); no transcendentals.
__global__ __launch_bounds__(256) void pq_k1(const float4* __restrict__ wr,
                                             const float4* __restrict__ wi,
                                             int n4, float* __restrict__ psre,
                                             float* __restrict__ psim,
                                             unsigned* __restrict__ pcnt) {
  float sre = 0.f, sim = 0.f;
  unsigned cnt = 0u;
  int stride = gridDim.x * blockDim.x;
  for (int i = blockIdx.x * blockDim.x + threadIdx.x; i < n4; i += stride) {
    float4 r = wr[i], g = wi[i];
    float xs[4] = {r.x, r.y, r.z, r.w};
    float ys[4] = {g.x, g.y, g.z, g.w};
    #pragma unroll
    for (int k = 0; k < 4; ++k) {
      float ax = fabsf(xs[k]), ay = fabsf(ys[k]);
      bool is_re = (ay <= ax);
      sre += is_re ? ax : 0.f;
      sim += is_re ? 0.f : ay;
      cnt += is_re ? 1u : 0u;
    }
  }
  block_reduce3(sre, sim, cnt);
  if (threadIdx.x == 0) {
    psre[blockIdx.x] = sre;
    psim[blockIdx.x] = sim;
    pcnt[blockIdx.x] = cnt;
  }
}

// Reduce NBLK partials -> finalized scales finals[0]=s_re, finals[1]=s_im.
__global__ __launch_bounds__(1024) void pq_reduce(const float* __restrict__ psre,
                                                  const float* __restrict__ psim,
                                                  const unsigned* __restrict__ pcnt,
                                                  unsigned nm,
                                                  float* __restrict__ finals) {
  float sre = 0.f, sim = 0.f;
  unsigned cnt = 0u;
  for (int i = threadIdx.x; i < NBLK; i += 1024) {
    sre += psre[i];
    sim += psim[i];
    cnt += pcnt[i];
  }
  block_reduce3(sre, sim, cnt);
  if (threadIdx.x == 0) {
    finals[0] = finalize_s(sre, cnt);
    finals[1] = finalize_s(sim, nm - cnt);
  }
}

// K2: recompute step 1, accumulate step-2 scale partials.
__global__ __launch_bounds__(256) void pq_k2(const float4* __restrict__ wr,
                                             const float4* __restrict__ wi,
                                             int n4,
                                             const float* __restrict__ temp,
                                             const float* __restrict__ finals1,
                                             float* __restrict__ psre,
                                             float* __restrict__ psim,
                                             unsigned* __restrict__ pcnt) {
  float s_re = finals1[0], s_im = finals1[1];
  float it = __builtin_amdgcn_rcpf(temp[0] + 1e-6f);
  float k_t = NM_PI * it;
  float c1 = __expf(-NM_PI2_4 * it);
  float c2 = __expf(-NM_PISQ * it);
  float sre = 0.f, sim = 0.f;
  unsigned cnt = 0u;
  int stride = gridDim.x * blockDim.x;
  for (int i = blockIdx.x * blockDim.x + threadIdx.x; i < n4; i += stride) {
    float4 r = wr[i], g = wi[i];
    float xs[4] = {r.x, r.y, r.z, r.w};
    float ys[4] = {g.x, g.y, g.z, g.w};
    #pragma unroll
    for (int k = 0; k < 4; ++k) {
      float x = xs[k], y = ys[k];
      float dre, dim;
      soft_dirs(x, y, k_t, c1, c2, dre, dim);
      float er = x - dre * s_re;
      float ei = y - dim * s_im;
      float ax = fabsf(er), ay = fabsf(ei);
      bool is_re = (ay <= ax);
      sre += is_re ? ax : 0.f;
      sim += is_re ? 0.f : ay;
      cnt += is_re ? 1u : 0u;
    }
  }
  block_reduce3(sre, sim, cnt);
  if (threadIdx.x == 0) {
    psre[blockIdx.x] = sre;
    psim[blockIdx.x] = sim;
    pcnt[blockIdx.x] = cnt;
  }
}

// K3: recompute steps 1+2, write qw_real / qw_imag.
// Non-temporal STORES only (output never re-read; preserve input residue in
// L3). Loads stay normal — next iteration's K1 re-reads the input.
__global__ __launch_bounds__(256) void pq_k3(const float4* __restrict__ wr,
                                             const float4* __restrict__ wi,
                                             int n4,
                                             const float* __restrict__ temp,
                                             const float* __restrict__ finals1,
                                             const float* __restrict__ finals2,
                                             float4* __restrict__ out) {
  f32x4* out4 = reinterpret_cast<f32x4*>(out);
  float s_re1 = finals1[0], s_im1 = finals1[1];
  float s_re2 = finals2[0], s_im2 = finals2[1];
  float it = __builtin_amdgcn_rcpf(temp[0] + 1e-6f);
  float k_t = NM_PI * it;
  float c1 = __expf(-NM_PI2_4 * it);
  float c2 = __expf(-NM_PISQ * it);
  int stride = gridDim.x * blockDim.x;
  for (int i = blockIdx.x * blockDim.x + threadIdx.x; i < n4; i += stride) {
    float4 r = wr[i], g = wi[i];
    float xs[4] = {r.x, r.y, r.z, r.w};
    float ys[4] = {g.x, g.y, g.z, g.w};
    float qr[4], qi[4];
    #pragma unroll
    for (int k = 0; k < 4; ++k) {
      float x = xs[k], y = ys[k];
      float d1re, d1im;
      soft_dirs(x, y, k_t, c1, c2, d1re, d1im);
      float q1r = d1re * s_re1;
      float q1i = d1im * s_im1;
      float er = x - q1r;
      float ei = y - q1i;
      float d2re, d2im;
      soft_dirs(er, ei, k_t, c1, c2, d2re, d2im);
      qr[k] = fmaf(d2re, s_re2, q1r);
      qi[k] = fmaf(d2im, s_im2, q1i);
    }
    f32x4 o0 = {qr[0], qr[1], qr[2], qr[3]};
    f32x4 o1 = {qi[0], qi[1], qi[2], qi[3]};
    __builtin_nontemporal_store(o0, &out4[i]);
    __builtin_nontemporal_store(o1, &out4[n4 + i]);
  }
}

extern "C" void kernel_launch(void* const* d_in, const int* in_sizes, int n_in,
                              void* d_out, int out_size, void* d_ws, size_t ws_size,
                              hipStream_t stream) {
  const float4* wr = (const float4*)d_in[0];
  const float4* wi = (const float4*)d_in[1];
  const float* temp = (const float*)d_in[2];
  int nm = in_sizes[0];
  int n4 = nm / 4;

  // ws layout (4B words):
  //   [0..7]                 finals: 0=s_re1 1=s_im1 2=s_re2 3=s_im2
  //   [8        .. 8+NB)     p1_sre
  //   [8+NB     .. 8+2NB)    p1_sim
  //   [8+2NB    .. 8+3NB)    p1_cnt (uint)
  //   [8+3NB    .. 8+6NB)    pass-2 partials, same order
  float* w32 = (float*)d_ws;
  unsigned* u32 = (unsigned*)d_ws;
  float* finals1 = w32 + 0;
  float* finals2 = w32 + 2;
  float* p1_sre = w32 + 8;
  float* p1_sim = p1_sre + NBLK;
  unsigned* p1_cnt = u32 + 8 + 2 * NBLK;
  float* p2_sre = w32 + 8 + 3 * NBLK;
  float* p2_sim = p2_sre + NBLK;
  unsigned* p2_cnt = u32 + 8 + 5 * NBLK;

  dim3 block(TPB);
  dim3 grid(NBLK);
  pq_k1<<<grid, block, 0, stream>>>(wr, wi, n4, p1_sre, p1_sim, p1_cnt);
  pq_reduce<<<1, 1024, 0, stream>>>(p1_sre, p1_sim, p1_cnt, (unsigned)nm, finals1);
  pq_k2<<<grid, block, 0, stream>>>(wr, wi, n4, temp, finals1,
                                    p2_sre, p2_sim, p2_cnt);
  pq_reduce<<<1, 1024, 0, stream>>>(p2_sre, p2_sim, p2_cnt, (unsigned)nm, finals2);
  pq_k3<<<grid, block, 0, stream>>>(wr, wi, n4, temp, finals1, finals2,
                                    (float4*)d_out);
}